// Round 1
// baseline (421.450 us; speedup 1.0000x reference)
//
#include <hip/hip_runtime.h>
#include <math.h>

#define Cc 32
#define Hc 128
#define Wc 160
#define Dc 48
#define HWc (Hc*Wc)
#define TS 16
#define HALO (TS+2)          // 18
#define NPOS (HALO*HALO)     // 324
#define DCHUNK 8
#define NCHUNK (Dc/DCHUNK)   // 6

// ---------------- kernel 1: projection matrices ----------------
// proj: (1,3,4,4). Compute proj_v @ inv(proj_0) for v=1,2; store rot(9)+trans(3).
__global__ void k_proj(const float* __restrict__ proj, float* __restrict__ wsproj) {
    if (threadIdx.x != 0 || blockIdx.x != 0) return;
    float a[4][8];
    for (int i = 0; i < 4; i++)
        for (int j = 0; j < 4; j++) {
            a[i][j]     = proj[i * 4 + j];
            a[i][j + 4] = (i == j) ? 1.f : 0.f;
        }
    // Gauss-Jordan with partial pivoting
    for (int col = 0; col < 4; col++) {
        int piv = col; float best = fabsf(a[col][col]);
        for (int r = col + 1; r < 4; r++) {
            float v = fabsf(a[r][col]);
            if (v > best) { best = v; piv = r; }
        }
        if (piv != col)
            for (int j = 0; j < 8; j++) { float t = a[col][j]; a[col][j] = a[piv][j]; a[piv][j] = t; }
        float inv = 1.f / a[col][col];
        for (int j = 0; j < 8; j++) a[col][j] *= inv;
        for (int r = 0; r < 4; r++) if (r != col) {
            float f = a[r][col];
            for (int j = 0; j < 8; j++) a[r][j] -= f * a[col][j];
        }
    }
    for (int v = 1; v < 3; v++) {
        const float* P = proj + v * 16;
        float M[3][4];
        for (int i = 0; i < 3; i++)
            for (int j = 0; j < 4; j++) {
                float s = 0.f;
                for (int k = 0; k < 4; k++) s += P[i * 4 + k] * a[k][4 + j];
                M[i][j] = s;
            }
        float* o = wsproj + (v - 1) * 12;
        o[0] = M[0][0]; o[1] = M[0][1]; o[2] = M[0][2];
        o[3] = M[1][0]; o[4] = M[1][1]; o[5] = M[1][2];
        o[6] = M[2][0]; o[7] = M[2][1]; o[8] = M[2][2];
        o[9] = M[0][3]; o[10] = M[1][3]; o[11] = M[2][3];
    }
}

// ---------------- kernel 2: fused warp + variance + 3D conv ----------------
__global__ __launch_bounds__(256, 2) void k_cost(
    const float* __restrict__ f0, const float* __restrict__ f1, const float* __restrict__ f2,
    const float* __restrict__ dvals, const float* __restrict__ wreg, const float* __restrict__ breg,
    const float* __restrict__ wsproj, float* __restrict__ costvol)
{
    __shared__ float var_l[Cc][NPOS];
    __shared__ float w_l[Cc * 27];
    __shared__ float projl[24];

    const int tid = threadIdx.x;
    for (int i = tid; i < Cc * 27; i += 256) w_l[i] = wreg[i];
    if (tid < 24) projl[tid] = wsproj[tid];
    __syncthreads();

    const int tileX = blockIdx.x;           // 0..9
    const int tileY = blockIdx.y;           // 0..7
    const int d0    = blockIdx.z * DCHUNK;  // 0,8,..,40
    const int tx = tid & 15, ty = tid >> 4;
    const int baseH = tileY * TS - 1, baseW = tileX * TS - 1;

    // two halo positions per thread (324 positions, 256 threads)
    float rx[2][2], ry[2][2], rz[2][2];
    bool  inimg[2];
    int   ridx[2];
    for (int s = 0; s < 2; s++) {
        int p = tid + s * 256;
        bool act = p < NPOS;
        int pp = act ? p : 0;
        int py = pp / HALO, px = pp % HALO;
        int hy = baseH + py, hx = baseW + px;
        inimg[s] = act && hy >= 0 && hy < Hc && hx >= 0 && hx < Wc;
        ridx[s] = inimg[s] ? (hy * Wc + hx) : 0;
        for (int v = 0; v < 2; v++) {
            const float* R = projl + v * 12;
            rx[s][v] = R[0] * hx + R[1] * hy + R[2];
            ry[s][v] = R[3] * hx + R[4] * hy + R[5];
            rz[s][v] = R[6] * hx + R[7] * hy + R[8];
        }
    }

    float cost[DCHUNK];
#pragma unroll
    for (int i = 0; i < DCHUNK; i++) cost[i] = 0.f;

    for (int dp = d0 - 1; dp <= d0 + DCHUNK; dp++) {
        if (dp < 0 || dp >= Dc) continue;   // uniform across block
        const float depth = dvals[dp];
        __syncthreads();                     // prior conv reads finished

        // ---- variance slice into LDS ----
        for (int s = 0; s < 2; s++) {
            int p = tid + s * 256;
            if (p >= NPOS) break;
            if (!inimg[s]) {
#pragma unroll 4
                for (int c = 0; c < Cc; c++) var_l[c][p] = 0.f;
            } else {
                float cw[2][4]; int ci[2][4];
                for (int v = 0; v < 2; v++) {
                    const float* R = projl + v * 12;
                    float X = fmaf(rx[s][v], depth, R[9]);
                    float Y = fmaf(ry[s][v], depth, R[10]);
                    float Z = fmaf(rz[s][v], depth, R[11]);
                    float iz = 1.f / Z;
                    float gx = X * iz, gy = Y * iz;
                    float x0f = floorf(gx), y0f = floorf(gy);
                    float wx = gx - x0f, wy = gy - y0f;
                    int x0 = (int)x0f, y0 = (int)y0f;
                    bool vx0 = (x0 >= 0) & (x0 <= Wc - 1);
                    bool vx1 = (x0 + 1 >= 0) & (x0 + 1 <= Wc - 1);
                    bool vy0 = (y0 >= 0) & (y0 <= Hc - 1);
                    bool vy1 = (y0 + 1 >= 0) & (y0 + 1 <= Hc - 1);
                    int xc0 = min(max(x0, 0), Wc - 1), xc1 = min(max(x0 + 1, 0), Wc - 1);
                    int yc0 = min(max(y0, 0), Hc - 1), yc1 = min(max(y0 + 1, 0), Hc - 1);
                    cw[v][0] = (1.f - wx) * (1.f - wy) * ((vx0 && vy0) ? 1.f : 0.f);
                    cw[v][1] = wx * (1.f - wy) * ((vx1 && vy0) ? 1.f : 0.f);
                    cw[v][2] = (1.f - wx) * wy * ((vx0 && vy1) ? 1.f : 0.f);
                    cw[v][3] = wx * wy * ((vx1 && vy1) ? 1.f : 0.f);
                    ci[v][0] = yc0 * Wc + xc0; ci[v][1] = yc0 * Wc + xc1;
                    ci[v][2] = yc1 * Wc + xc0; ci[v][3] = yc1 * Wc + xc1;
                }
                const int rr = ridx[s];
#pragma unroll 4
                for (int c = 0; c < Cc; c++) {
                    const int off = c * HWc;
                    float ref = f0[off + rr];
                    float a1 = cw[0][0] * f1[off + ci[0][0]] + cw[0][1] * f1[off + ci[0][1]]
                             + cw[0][2] * f1[off + ci[0][2]] + cw[0][3] * f1[off + ci[0][3]];
                    float a2 = cw[1][0] * f2[off + ci[1][0]] + cw[1][1] * f2[off + ci[1][1]]
                             + cw[1][2] * f2[off + ci[1][2]] + cw[1][3] * f2[off + ci[1][3]];
                    float sm = ref + a1 + a2;
                    float sq = ref * ref + a1 * a1 + a2 * a2;
                    var_l[c][p] = sq * (1.f / 3.f) - (sm * sm) * (1.f / 9.f);
                }
            }
        }
        __syncthreads();

        // ---- 3x3 spatial conv for the three kd planes ----
        float a0 = 0.f, a1 = 0.f, a2 = 0.f;
#pragma unroll 4
        for (int c = 0; c < Cc; c++) {
            const float* wl = w_l + c * 27;
#pragma unroll
            for (int kh = 0; kh < 3; kh++) {
#pragma unroll
                for (int kw = 0; kw < 3; kw++) {
                    float v = var_l[c][(ty + kh) * HALO + (tx + kw)];
                    a0 = fmaf(v, wl[0 * 9 + kh * 3 + kw], a0);
                    a1 = fmaf(v, wl[1 * 9 + kh * 3 + kw], a1);
                    a2 = fmaf(v, wl[2 * 9 + kh * 3 + kw], a2);
                }
            }
        }
        // cost(d) = A0(d-1) + A1(d) + A2(d+1)
        int r;
        r = dp + 1 - d0; if (r >= 0 && r < DCHUNK) cost[r] += a0;
        r = dp - d0;     if (r >= 0 && r < DCHUNK) cost[r] += a1;
        r = dp - 1 - d0; if (r >= 0 && r < DCHUNK) cost[r] += a2;
    }

    const float bias = breg[0];
    const int h = tileY * TS + ty, w = tileX * TS + tx;
#pragma unroll
    for (int i = 0; i < DCHUNK; i++)
        costvol[(d0 + i) * HWc + h * Wc + w] = cost[i] + bias;
}

// ---------------- kernel 3: softmax over depth + regression ----------------
__global__ void k_softmax(const float* __restrict__ costvol, const float* __restrict__ dvals,
                          float* __restrict__ out)
{
    const int px = blockIdx.x * 256 + threadIdx.x;
    if (px >= HWc) return;
    float m = -1e30f;
    for (int d = 0; d < Dc; d++) m = fmaxf(m, costvol[d * HWc + px]);
    float se = 0.f, sed = 0.f, me = 0.f;
    for (int d = 0; d < Dc; d++) {
        float e = __expf(costvol[d * HWc + px] - m);
        se += e;
        sed = fmaf(e, dvals[d], sed);
        me = fmaxf(me, e);
    }
    float inv = 1.f / se;
    out[px]       = sed * inv;   // depth
    out[HWc + px] = me * inv;    // photometric confidence
}

extern "C" void kernel_launch(void* const* d_in, const int* in_sizes, int n_in,
                              void* d_out, int out_size, void* d_ws, size_t ws_size,
                              hipStream_t stream) {
    const float* f0    = (const float*)d_in[0];
    const float* f1    = (const float*)d_in[1];
    const float* f2    = (const float*)d_in[2];
    const float* proj  = (const float*)d_in[3];
    const float* dvals = (const float*)d_in[4];
    const float* wreg  = (const float*)d_in[5];
    const float* breg  = (const float*)d_in[6];

    float* ws      = (float*)d_ws;
    float* wsproj  = ws;        // 24 floats
    float* costvol = ws + 32;   // Dc*HWc floats = 3.93 MB

    k_proj<<<1, 64, 0, stream>>>(proj, wsproj);

    dim3 grid(Wc / TS, Hc / TS, NCHUNK);   // 10 x 8 x 6 = 480 blocks
    k_cost<<<grid, 256, 0, stream>>>(f0, f1, f2, dvals, wreg, breg, wsproj, costvol);

    k_softmax<<<HWc / 256, 256, 0, stream>>>(costvol, dvals, (float*)d_out);
}